// Round 15
// baseline (848.008 us; speedup 1.0000x reference)
//
#include <hip/hip_runtime.h>
#include <cstdint>
#include <cstddef>

#define NPTS 500000
#define CIN  128
#define GCH  256
#define COUT 128
#define KTAP 27

typedef __attribute__((ext_vector_type(4))) float    f32x4;
typedef __attribute__((ext_vector_type(2))) float    f32x2;
typedef __attribute__((ext_vector_type(8))) short    s16x8;
typedef __attribute__((ext_vector_type(4))) uint32_t u32x4;
typedef __attribute__((ext_vector_type(2))) uint32_t u32x2;

__device__ __forceinline__ unsigned short f2bf(float f) {
  union { float f; uint32_t u; } v; v.f = f;
  uint32_t r = v.u + 0x7FFFu + ((v.u >> 16) & 1u);
  return (unsigned short)(r >> 16);
}
__device__ __forceinline__ float bf2f(unsigned short h) {
  union { uint32_t u; float f; } v; v.u = ((uint32_t)h) << 16;
  return v.f;
}
// HW packed f32->bf16 (RNE), 1 instr for 2 values
__device__ __forceinline__ uint32_t cvt2bf(float a, float b) {
  uint32_t r;
  asm("v_cvt_pk_bf16_f32 %0, %1, %2" : "=v"(r) : "v"(a), "v"(b));
  return r;
}

// ---------- prep: W1 bf16 frags + W2 fp8 frags + zero GRN sums ----------
__global__ __launch_bounds__(256) void k_prep(
    const float* __restrict__ W1, const float* __restrict__ W2,
    unsigned short* __restrict__ W1t, uint8_t* __restrict__ W2t8,
    float* __restrict__ sums) {
  int b = blockIdx.x, t = threadIdx.x;
  if (b == 0 && t < COUT) sums[t] = 0.f;
  int gt = (b & 15) * 256 + t;      // 0..4095
  int grp = gt >> 6, lane = gt & 63;
  int l15 = lane & 15, l4 = lane >> 4;
  if (b < 16) {
    int f = grp >> 2, s = grp & 3;                 // 16 col-tiles x 4 k-steps
    int col = f * 16 + l15, k0 = s * 32 + l4 * 8;
    unsigned short* dst = W1t + gt * 8;
#pragma unroll
    for (int j = 0; j < 8; ++j) dst[j] = f2bf(W1[(size_t)(k0 + j) * GCH + col]);
  } else {
    int f = grp >> 3, s = grp & 7;                 // 8 col-tiles x 8 k-steps
    int col = f * 16 + l15, k0 = s * 32 + l4 * 8;
    float w[8];
#pragma unroll
    for (int e = 0; e < 8; ++e) w[e] = W2[(size_t)(k0 + e) * COUT + col];
    int lo = __builtin_amdgcn_cvt_pk_fp8_f32(w[0], w[1], 0, false);
    lo = __builtin_amdgcn_cvt_pk_fp8_f32(w[2], w[3], lo, true);
    int hi = __builtin_amdgcn_cvt_pk_fp8_f32(w[4], w[5], 0, false);
    hi = __builtin_amdgcn_cvt_pk_fp8_f32(w[6], w[7], hi, true);
    u32x2 q = {(uint32_t)lo, (uint32_t)hi};
    *(u32x2*)(W2t8 + gt * 8) = q;
  }
}

// ---------- K1: h1 = LN(x @ W1 + b1) -> fp8 [N][256] ----------
// r14 structure; x->bf16 via v_cvt_pk_bf16_f32 (16 instrs vs 256 sw-rounded).
__global__ __launch_bounds__(512) void k_gemm1_ln(
    const float* __restrict__ x, const unsigned short* __restrict__ W1t,
    const float* __restrict__ b1, const float* __restrict__ ln_g,
    const float* __restrict__ ln_b, uint8_t* __restrict__ h1f8) {
  __shared__ unsigned short Wl[4096 * 8];      // 64 KB frag-linear W1
  __shared__ float lnbuf[8][16][2];            // 1 KB: cross-wave LN partials
  int tid = threadIdx.x, lane = tid & 63, wv = tid >> 6;
  int l15 = lane & 15, l4 = lane >> 4;
  int wr = wv >> 1, wc = wv & 1;               // row-group 0..3, col-half 0..1
  long rowbase = (long)blockIdx.x * 128;

  long gr0 = rowbase + wr * 16 + l15;
  long gr1 = gr0 + 64;
  bool ok0 = gr0 < NPTS, ok1 = gr1 < NPTS;
  const float* xp0 = x + gr0 * CIN + l4 * 8;
  const float* xp1 = x + gr1 * CIN + l4 * 8;
  f32x4 xv[16];
#pragma unroll
  for (int s = 0; s < 4; ++s) {
    xv[2 * s] = ok0 ? *(const f32x4*)(xp0 + s * 32) : (f32x4){0, 0, 0, 0};
    xv[2 * s + 1] = ok0 ? *(const f32x4*)(xp0 + s * 32 + 4) : (f32x4){0, 0, 0, 0};
  }
#pragma unroll
  for (int s = 0; s < 4; ++s) {
    xv[8 + 2 * s] = ok1 ? *(const f32x4*)(xp1 + s * 32) : (f32x4){0, 0, 0, 0};
    xv[8 + 2 * s + 1] = ok1 ? *(const f32x4*)(xp1 + s * 32 + 4) : (f32x4){0, 0, 0, 0};
  }

#pragma unroll
  for (int i = 0; i < 8; ++i) {                // stage W1t -> LDS, coalesced
    int off = (i * 512 + tid) * 8;
    *(s16x8*)&Wl[off] = *(const s16x8*)&W1t[off];
  }

  s16x8 a0[4], a1[4];
#pragma unroll
  for (int s = 0; s < 4; ++s) {
    f32x4 v0 = xv[2 * s], v1 = xv[2 * s + 1];
    u32x4 q;
    q[0] = cvt2bf(v0[0], v0[1]); q[1] = cvt2bf(v0[2], v0[3]);
    q[2] = cvt2bf(v1[0], v1[1]); q[3] = cvt2bf(v1[2], v1[3]);
    a0[s] = *(s16x8*)&q;
    v0 = xv[8 + 2 * s]; v1 = xv[8 + 2 * s + 1];
    u32x4 p;
    p[0] = cvt2bf(v0[0], v0[1]); p[1] = cvt2bf(v0[2], v0[3]);
    p[2] = cvt2bf(v1[0], v1[1]); p[3] = cvt2bf(v1[2], v1[3]);
    a1[s] = *(s16x8*)&p;
  }
  __syncthreads();

  // ---------------- tile 0 ----------------
  {
    f32x4 acc[8];
#pragma unroll
    for (int f = 0; f < 8; ++f) acc[f] = (f32x4){0.f, 0.f, 0.f, 0.f};
#pragma unroll
    for (int f = 0; f < 8; ++f)
#pragma unroll
      for (int s = 0; s < 4; ++s) {
        s16x8 w = *(const s16x8*)&Wl[(((wc * 8 + f) * 4 + s) * 64 + lane) * 8];
        acc[f] = __builtin_amdgcn_mfma_f32_16x16x32_bf16(w, a0[s], acc[f], 0, 0, 0);
      }
    float s1 = 0.f, s2 = 0.f;
#pragma unroll
    for (int f = 0; f < 8; ++f) {
      f32x4 bb = *(const f32x4*)(b1 + wc * 128 + f * 16 + l4 * 4);
#pragma unroll
      for (int j = 0; j < 4; ++j) {
        float v = acc[f][j] + bb[j];
        acc[f][j] = v;
        s1 += v; s2 += v * v;
      }
    }
    s1 += __shfl_xor(s1, 16); s1 += __shfl_xor(s1, 32);
    s2 += __shfl_xor(s2, 16); s2 += __shfl_xor(s2, 32);
    if (lane < 16) { lnbuf[wv][l15][0] = s1; lnbuf[wv][l15][1] = s2; }
    __syncthreads();
    float t1 = s1 + lnbuf[wv ^ 1][l15][0];
    float t2 = s2 + lnbuf[wv ^ 1][l15][1];
    float mu = t1 * (1.f / GCH);
    float var = t2 * (1.f / GCH) - mu * mu;
    float rs = rsqrtf(var + 1e-6f);
    uint8_t* dp = h1f8 + gr0 * GCH + wc * 128 + l4 * 4;
#pragma unroll
    for (int f = 0; f < 8; ++f) {
      f32x4 g4 = *(const f32x4*)(ln_g + wc * 128 + f * 16 + l4 * 4);
      f32x4 b4 = *(const f32x4*)(ln_b + wc * 128 + f * 16 + l4 * 4);
      float v0 = (acc[f][0] - mu) * rs * g4[0] + b4[0];
      float v1 = (acc[f][1] - mu) * rs * g4[1] + b4[1];
      float v2 = (acc[f][2] - mu) * rs * g4[2] + b4[2];
      float v3 = (acc[f][3] - mu) * rs * g4[3] + b4[3];
      int w0 = __builtin_amdgcn_cvt_pk_fp8_f32(v0, v1, 0, false);
      w0 = __builtin_amdgcn_cvt_pk_fp8_f32(v2, v3, w0, true);
      if (ok0) *(uint32_t*)(dp + f * 16) = (uint32_t)w0;
    }
  }
  __syncthreads();   // lnbuf write-after-read guard between tiles

  // ---------------- tile 1 ----------------
  {
    f32x4 acc[8];
#pragma unroll
    for (int f = 0; f < 8; ++f) acc[f] = (f32x4){0.f, 0.f, 0.f, 0.f};
#pragma unroll
    for (int f = 0; f < 8; ++f)
#pragma unroll
      for (int s = 0; s < 4; ++s) {
        s16x8 w = *(const s16x8*)&Wl[(((wc * 8 + f) * 4 + s) * 64 + lane) * 8];
        acc[f] = __builtin_amdgcn_mfma_f32_16x16x32_bf16(w, a1[s], acc[f], 0, 0, 0);
      }
    float s1 = 0.f, s2 = 0.f;
#pragma unroll
    for (int f = 0; f < 8; ++f) {
      f32x4 bb = *(const f32x4*)(b1 + wc * 128 + f * 16 + l4 * 4);
#pragma unroll
      for (int j = 0; j < 4; ++j) {
        float v = acc[f][j] + bb[j];
        acc[f][j] = v;
        s1 += v; s2 += v * v;
      }
    }
    s1 += __shfl_xor(s1, 16); s1 += __shfl_xor(s1, 32);
    s2 += __shfl_xor(s2, 16); s2 += __shfl_xor(s2, 32);
    if (lane < 16) { lnbuf[wv][l15][0] = s1; lnbuf[wv][l15][1] = s2; }
    __syncthreads();
    float t1 = s1 + lnbuf[wv ^ 1][l15][0];
    float t2 = s2 + lnbuf[wv ^ 1][l15][1];
    float mu = t1 * (1.f / GCH);
    float var = t2 * (1.f / GCH) - mu * mu;
    float rs = rsqrtf(var + 1e-6f);
    uint8_t* dp = h1f8 + gr1 * GCH + wc * 128 + l4 * 4;
#pragma unroll
    for (int f = 0; f < 8; ++f) {
      f32x4 g4 = *(const f32x4*)(ln_g + wc * 128 + f * 16 + l4 * 4);
      f32x4 b4 = *(const f32x4*)(ln_b + wc * 128 + f * 16 + l4 * 4);
      float v0 = (acc[f][0] - mu) * rs * g4[0] + b4[0];
      float v1 = (acc[f][1] - mu) * rs * g4[1] + b4[1];
      float v2 = (acc[f][2] - mu) * rs * g4[2] + b4[2];
      float v3 = (acc[f][3] - mu) * rs * g4[3] + b4[3];
      int w0 = __builtin_amdgcn_cvt_pk_fp8_f32(v0, v1, 0, false);
      w0 = __builtin_amdgcn_cvt_pk_fp8_f32(v2, v3, w0, true);
      if (ok1) *(uint32_t*)(dp + f * 16) = (uint32_t)w0;
    }
  }
}

// ---------- K2+K4 fused: gather -> fp8 LDS tile -> fp8 MFMA -> gelu -> h3 fp8 ----------
// r14 body (76.8 KB LDS = 2 blocks/CU, coalesced h3 repack epilogue).
__global__ __launch_bounds__(512) void k_dwg2(
    const uint8_t* __restrict__ h1f8, const int* __restrict__ nbr,
    const float* __restrict__ dw_w, const float* __restrict__ dw_b,
    const uint8_t* __restrict__ W2t8, const float* __restrict__ b2,
    uint8_t* __restrict__ h3f8, float* __restrict__ sums) {
  __shared__ float wf[KTAP * 4 * 16 * 4];   // 27648 B [k][j][l15][4] (2-way banks, free)
  __shared__ int idxl[128 * KTAP];          // 13824 B
  __shared__ uint8_t Al[128][GCH + 16];     // 34816 B fp8 h2 tile; reused as h3 tile [128][144]
  __shared__ float ssum[COUT];              // 512 B   -> 76800 B total, 2 blocks/CU
  int tid = threadIdx.x, lane = tid & 63, wv = tid >> 6;
  int l15 = lane & 15, l4 = lane >> 4;
  size_t pblk = (size_t)blockIdx.x * 128;

  for (int u = tid; u < KTAP * 64; u += 512) {   // stage dw weights f32
    int g = u >> 4, ld = u & 15, k = g >> 2, j = g & 3;
    *(f32x4*)&wf[u * 4] = *(const f32x4*)(dw_w + k * GCH + ld * 16 + j * 4);
  }
  if (tid < COUT) ssum[tid] = 0.f;
  for (int i = tid; i < 128 * KTAP; i += 512) {  // stage indices
    size_t gi = pblk * KTAP + i;
    idxl[i] = (gi < (size_t)NPTS * KTAP) ? __builtin_nontemporal_load(nbr + gi) : 0;
  }
  __syncthreads();

  {                                              // ---- gather phase ----
    f32x2 bias[8];
#pragma unroll
    for (int d = 0; d < 4; ++d) {
      f32x4 b4 = *(const f32x4*)(dw_b + l15 * 16 + d * 4);
      bias[2 * d]     = (f32x2){b4[0], b4[1]};
      bias[2 * d + 1] = (f32x2){b4[2], b4[3]};
    }
    int coff = l15 * 16;
#pragma unroll
    for (int it = 0; it < 4; ++it) {
      int pl = it * 32 + wv * 4 + l4;            // 0..127
      f32x2 acc[8];
#pragma unroll
      for (int i = 0; i < 8; ++i) acc[i] = bias[i];
#pragma unroll
      for (int k = 0; k < KTAP; ++k) {
        int row = idxl[pl * KTAP + k];           // LDS broadcast per 16-lane group
        u32x4 hv = *(const u32x4*)(h1f8 + ((size_t)(uint32_t)row << 8) + coff);
#pragma unroll
        for (int j = 0; j < 4; ++j) {
          f32x4 w4 = *(const f32x4*)&wf[((k * 4 + j) * 16 + l15) * 4];
          f32x2 lo = __builtin_amdgcn_cvt_pk_f32_fp8(hv[j], false);
          f32x2 hi = __builtin_amdgcn_cvt_pk_f32_fp8(hv[j], true);
          acc[2 * j]     += lo * (f32x2){w4[0], w4[1]};
          acc[2 * j + 1] += hi * (f32x2){w4[2], w4[3]};
        }
      }
      u32x4 o;
#pragma unroll
      for (int j = 0; j < 4; ++j) {
        int u = __builtin_amdgcn_cvt_pk_fp8_f32(acc[2 * j][0], acc[2 * j][1], 0, false);
        u = __builtin_amdgcn_cvt_pk_fp8_f32(acc[2 * j + 1][0], acc[2 * j + 1][1], u, true);
        o[j] = (uint32_t)u;
      }
      *(u32x4*)&Al[pl][coff] = o;                // h2 tile stays in LDS
    }
  }
  __syncthreads();

  // ---- MFMA phase (fp8 h2-tile @ W2) ----
  f32x4 acc[8];
#pragma unroll
  for (int f = 0; f < 8; ++f) acc[f] = (f32x4){0.f, 0.f, 0.f, 0.f};
  long aa[8];
#pragma unroll
  for (int s = 0; s < 8; ++s)
    aa[s] = *(const long*)&Al[wv * 16 + l15][s * 32 + l4 * 8];
  __syncthreads();                               // all Al reads done -> reuse as h3 tile
#pragma unroll
  for (int f = 0; f < 8; ++f)
#pragma unroll
    for (int s = 0; s < 8; ++s) {
      long bb = *(const long*)&W2t8[((f * 8 + s) * 64 + lane) * 8];  // L2-hot 32 KB
      acc[f] = __builtin_amdgcn_mfma_f32_16x16x32_fp8_fp8(aa[s], bb, acc[f], 0, 0, 0);
    }

  uint8_t* h3l = &Al[0][0];                      // [128][144] byte tile
#pragma unroll
  for (int f = 0; f < 8; ++f) {
    int col = f * 16 + l15;
    float bbv = b2[col];
    float ps = 0.f;
#pragma unroll
    for (int j = 0; j < 4; ++j) {
      int rl = wv * 16 + l4 * 4 + j;
      float v = acc[f][j] + bbv;
      // tanh-GELU in sigmoid form (max |diff| vs erf-GELU ~3e-4)
      float u = 1.5957691216f * (v + 0.044715f * v * v * v);
      float g = v * __frcp_rn(1.f + __expf(-u));
      uint32_t w8 = (uint32_t)__builtin_amdgcn_cvt_pk_fp8_f32(g, g, 0, false);
      h3l[rl * 144 + col] = (uint8_t)(w8 & 0xFF);
      if ((long)pblk + rl < NPTS) ps += g * g;
    }
    ps += __shfl_xor(ps, 16);
    ps += __shfl_xor(ps, 32);
    if (l4 == 0) atomicAdd(&ssum[col], ps);
  }
  __syncthreads();

  // coalesced write-out: 8 threads/row, full 128-B rows per instruction
#pragma unroll
  for (int p = 0; p < 2; ++p) {
    int row = p * 64 + (tid >> 3);
    long r = (long)pblk + row;
    if (r < NPTS) {
      u32x4 q = *(const u32x4*)&h3l[row * 144 + (tid & 7) * 16];
      __builtin_nontemporal_store(q, (u32x4*)(h3f8 + r * COUT + (tid & 7) * 16));
    }
  }
  if (tid < COUT) atomicAdd(&sums[tid], ssum[tid]);
}

// ---------- K5: GRN finalize -> scale/shift tables ----------
__global__ void k_grn(const float* __restrict__ sums, const float* __restrict__ grn_g,
                      const float* __restrict__ grn_b, float* __restrict__ sAB) {
  __shared__ float gx[COUT];
  __shared__ float mean_s;
  int t = threadIdx.x;
  float g = sqrtf(sums[t]);
  gx[t] = g;
  __syncthreads();
  if (t == 0) {
    float s = 0.f;
    for (int i = 0; i < COUT; ++i) s += gx[i];
    mean_s = s * (1.f / COUT);
  }
  __syncthreads();
  float nx = g / (mean_s + 1e-6f);
  sAB[t] = grn_g[t] * nx + 1.f;
  sAB[COUT + t] = grn_b[t];
}

// ---------- K6: out = h3*sA + sB + x (h3 is fp8) ----------
__global__ __launch_bounds__(256) void k_final(
    const uint8_t* __restrict__ h3f8, const float* __restrict__ x,
    const float* __restrict__ sAB, float* __restrict__ out) {
  long q = (long)blockIdx.x * 256 + threadIdx.x;
  long idx = q * 4;
  int c0 = (int)(idx & (COUT - 1));
  f32x4 sA = *(const f32x4*)(sAB + c0);
  f32x4 sB = *(const f32x4*)(sAB + COUT + c0);
  uint32_t hv = *(const uint32_t*)(h3f8 + idx);
  f32x2 lo = __builtin_amdgcn_cvt_pk_f32_fp8(hv, false);
  f32x2 hi = __builtin_amdgcn_cvt_pk_f32_fp8(hv, true);
  f32x4 xv = __builtin_nontemporal_load((const f32x4*)(x + idx));
  f32x4 r;
  r[0] = lo[0] * sA[0] + sB[0] + xv[0];
  r[1] = lo[1] * sA[1] + sB[1] + xv[1];
  r[2] = hi[0] * sA[2] + sB[2] + xv[2];
  r[3] = hi[1] * sA[3] + sB[3] + xv[3];
  __builtin_nontemporal_store(r, (f32x4*)(out + idx));
}

extern "C" void kernel_launch(void* const* d_in, const int* in_sizes, int n_in,
                              void* d_out, int out_size, void* d_ws, size_t ws_size,
                              hipStream_t stream) {
  const float* x     = (const float*)d_in[0];
  const int*   nbr   = (const int*)d_in[1];
  const float* W1    = (const float*)d_in[2];
  const float* b1    = (const float*)d_in[3];
  const float* ln_g  = (const float*)d_in[4];
  const float* ln_b  = (const float*)d_in[5];
  const float* dw_w  = (const float*)d_in[6];
  const float* dw_b  = (const float*)d_in[7];
  const float* W2    = (const float*)d_in[8];
  const float* b2    = (const float*)d_in[9];
  const float* grn_g = (const float*)d_in[10];
  const float* grn_b = (const float*)d_in[11];
  float* out = (float*)d_out;

  char* ws = (char*)d_ws;
  uint8_t* h1f8       = (uint8_t*)ws;                                // 128 MB
  uint8_t* h3f8       = (uint8_t*)(ws + (size_t)NPTS * GCH);         // 64 MB
  size_t off = (size_t)NPTS * GCH + (size_t)NPTS * COUT;             // 192 MB
  unsigned short* W1t = (unsigned short*)(ws + off);                 // 64 KB
  uint8_t* W2t8       = (uint8_t*)(ws + off + 65536);                // 32 KB
  float* sums         = (float*)(ws + off + 65536 + 32768);
  float* sAB          = (float*)(ws + off + 65536 + 32768 + 512);

  k_prep<<<32, 256, 0, stream>>>(W1, W2, W1t, W2t8, sums);
  k_gemm1_ln<<<(NPTS + 127) / 128, 512, 0, stream>>>(x, W1t, b1, ln_g, ln_b, h1f8);
  k_dwg2<<<(NPTS + 127) / 128, 512, 0, stream>>>(h1f8, nbr, dw_w, dw_b, W2t8, b2, h3f8, sums);
  k_grn<<<1, COUT, 0, stream>>>(sums, grn_g, grn_b, sAB);
  k_final<<<(NPTS * COUT / 4) / 256, 256, 0, stream>>>(h3f8, x, sAB, out);
}

// Round 16
// 816.489 us; speedup vs baseline: 1.0386x; 1.0386x over previous
//
#include <hip/hip_runtime.h>
#include <cstdint>
#include <cstddef>

#define NPTS 500000
#define CIN  128
#define GCH  256
#define COUT 128
#define KTAP 27

typedef __attribute__((ext_vector_type(4))) float    f32x4;
typedef __attribute__((ext_vector_type(2))) float    f32x2;
typedef __attribute__((ext_vector_type(8))) short    s16x8;
typedef __attribute__((ext_vector_type(4))) uint32_t u32x4;
typedef __attribute__((ext_vector_type(2))) uint32_t u32x2;

__device__ __forceinline__ unsigned short f2bf(float f) {
  union { float f; uint32_t u; } v; v.f = f;
  uint32_t r = v.u + 0x7FFFu + ((v.u >> 16) & 1u);
  return (unsigned short)(r >> 16);
}
__device__ __forceinline__ float bf2f(unsigned short h) {
  union { uint32_t u; float f; } v; v.u = ((uint32_t)h) << 16;
  return v.f;
}

// ---------- prep: W1 bf16 frags + W2 fp8 frags + zero GRN sums ----------
__global__ __launch_bounds__(256) void k_prep(
    const float* __restrict__ W1, const float* __restrict__ W2,
    unsigned short* __restrict__ W1t, uint8_t* __restrict__ W2t8,
    float* __restrict__ sums) {
  int b = blockIdx.x, t = threadIdx.x;
  if (b == 0 && t < COUT) sums[t] = 0.f;
  int gt = (b & 15) * 256 + t;      // 0..4095
  int grp = gt >> 6, lane = gt & 63;
  int l15 = lane & 15, l4 = lane >> 4;
  if (b < 16) {
    int f = grp >> 2, s = grp & 3;                 // 16 col-tiles x 4 k-steps
    int col = f * 16 + l15, k0 = s * 32 + l4 * 8;
    unsigned short* dst = W1t + gt * 8;
#pragma unroll
    for (int j = 0; j < 8; ++j) dst[j] = f2bf(W1[(size_t)(k0 + j) * GCH + col]);
  } else {
    int f = grp >> 3, s = grp & 7;                 // 8 col-tiles x 8 k-steps
    int col = f * 16 + l15, k0 = s * 32 + l4 * 8;
    float w[8];
#pragma unroll
    for (int e = 0; e < 8; ++e) w[e] = W2[(size_t)(k0 + e) * COUT + col];
    int lo = __builtin_amdgcn_cvt_pk_fp8_f32(w[0], w[1], 0, false);
    lo = __builtin_amdgcn_cvt_pk_fp8_f32(w[2], w[3], lo, true);
    int hi = __builtin_amdgcn_cvt_pk_fp8_f32(w[4], w[5], 0, false);
    hi = __builtin_amdgcn_cvt_pk_fp8_f32(w[6], w[7], hi, true);
    u32x2 q = {(uint32_t)lo, (uint32_t)hi};
    *(u32x2*)(W2t8 + gt * 8) = q;
  }
}

// ---------- K1: h1 = LN(x @ W1 + b1) -> fp8 [N][256] (r14 body, unchanged) ----------
__global__ __launch_bounds__(512) void k_gemm1_ln(
    const float* __restrict__ x, const unsigned short* __restrict__ W1t,
    const float* __restrict__ b1, const float* __restrict__ ln_g,
    const float* __restrict__ ln_b, uint8_t* __restrict__ h1f8) {
  __shared__ unsigned short Wl[4096 * 8];      // 64 KB frag-linear W1
  __shared__ float lnbuf[8][16][2];            // 1 KB: cross-wave LN partials
  int tid = threadIdx.x, lane = tid & 63, wv = tid >> 6;
  int l15 = lane & 15, l4 = lane >> 4;
  int wr = wv >> 1, wc = wv & 1;               // row-group 0..3, col-half 0..1
  long rowbase = (long)blockIdx.x * 128;

  long gr0 = rowbase + wr * 16 + l15;
  long gr1 = gr0 + 64;
  bool ok0 = gr0 < NPTS, ok1 = gr1 < NPTS;
  const float* xp0 = x + gr0 * CIN + l4 * 8;
  const float* xp1 = x + gr1 * CIN + l4 * 8;
  f32x4 xv[16];
#pragma unroll
  for (int s = 0; s < 4; ++s) {
    xv[2 * s] = ok0 ? *(const f32x4*)(xp0 + s * 32) : (f32x4){0, 0, 0, 0};
    xv[2 * s + 1] = ok0 ? *(const f32x4*)(xp0 + s * 32 + 4) : (f32x4){0, 0, 0, 0};
  }
#pragma unroll
  for (int s = 0; s < 4; ++s) {
    xv[8 + 2 * s] = ok1 ? *(const f32x4*)(xp1 + s * 32) : (f32x4){0, 0, 0, 0};
    xv[8 + 2 * s + 1] = ok1 ? *(const f32x4*)(xp1 + s * 32 + 4) : (f32x4){0, 0, 0, 0};
  }

#pragma unroll
  for (int i = 0; i < 8; ++i) {                // stage W1t -> LDS, coalesced
    int off = (i * 512 + tid) * 8;
    *(s16x8*)&Wl[off] = *(const s16x8*)&W1t[off];
  }

  s16x8 a0[4], a1[4];
#pragma unroll
  for (int s = 0; s < 4; ++s) {
    f32x4 v0 = xv[2 * s], v1 = xv[2 * s + 1];
    s16x8 t;
    t[0] = (short)f2bf(v0[0]); t[1] = (short)f2bf(v0[1]);
    t[2] = (short)f2bf(v0[2]); t[3] = (short)f2bf(v0[3]);
    t[4] = (short)f2bf(v1[0]); t[5] = (short)f2bf(v1[1]);
    t[6] = (short)f2bf(v1[2]); t[7] = (short)f2bf(v1[3]);
    a0[s] = t;
    v0 = xv[8 + 2 * s]; v1 = xv[8 + 2 * s + 1];
    t[0] = (short)f2bf(v0[0]); t[1] = (short)f2bf(v0[1]);
    t[2] = (short)f2bf(v0[2]); t[3] = (short)f2bf(v0[3]);
    t[4] = (short)f2bf(v1[0]); t[5] = (short)f2bf(v1[1]);
    t[6] = (short)f2bf(v1[2]); t[7] = (short)f2bf(v1[3]);
    a1[s] = t;
  }
  __syncthreads();

  // ---------------- tile 0 ----------------
  {
    f32x4 acc[8];
#pragma unroll
    for (int f = 0; f < 8; ++f) acc[f] = (f32x4){0.f, 0.f, 0.f, 0.f};
#pragma unroll
    for (int f = 0; f < 8; ++f)
#pragma unroll
      for (int s = 0; s < 4; ++s) {
        s16x8 w = *(const s16x8*)&Wl[(((wc * 8 + f) * 4 + s) * 64 + lane) * 8];
        acc[f] = __builtin_amdgcn_mfma_f32_16x16x32_bf16(w, a0[s], acc[f], 0, 0, 0);
      }
    float s1 = 0.f, s2 = 0.f;
#pragma unroll
    for (int f = 0; f < 8; ++f) {
      f32x4 bb = *(const f32x4*)(b1 + wc * 128 + f * 16 + l4 * 4);
#pragma unroll
      for (int j = 0; j < 4; ++j) {
        float v = acc[f][j] + bb[j];
        acc[f][j] = v;
        s1 += v; s2 += v * v;
      }
    }
    s1 += __shfl_xor(s1, 16); s1 += __shfl_xor(s1, 32);
    s2 += __shfl_xor(s2, 16); s2 += __shfl_xor(s2, 32);
    if (lane < 16) { lnbuf[wv][l15][0] = s1; lnbuf[wv][l15][1] = s2; }
    __syncthreads();
    float t1 = s1 + lnbuf[wv ^ 1][l15][0];
    float t2 = s2 + lnbuf[wv ^ 1][l15][1];
    float mu = t1 * (1.f / GCH);
    float var = t2 * (1.f / GCH) - mu * mu;
    float rs = rsqrtf(var + 1e-6f);
    uint8_t* dp = h1f8 + gr0 * GCH + wc * 128 + l4 * 4;
#pragma unroll
    for (int f = 0; f < 8; ++f) {
      f32x4 g4 = *(const f32x4*)(ln_g + wc * 128 + f * 16 + l4 * 4);
      f32x4 b4 = *(const f32x4*)(ln_b + wc * 128 + f * 16 + l4 * 4);
      float v0 = (acc[f][0] - mu) * rs * g4[0] + b4[0];
      float v1 = (acc[f][1] - mu) * rs * g4[1] + b4[1];
      float v2 = (acc[f][2] - mu) * rs * g4[2] + b4[2];
      float v3 = (acc[f][3] - mu) * rs * g4[3] + b4[3];
      int w0 = __builtin_amdgcn_cvt_pk_fp8_f32(v0, v1, 0, false);
      w0 = __builtin_amdgcn_cvt_pk_fp8_f32(v2, v3, w0, true);
      if (ok0) *(uint32_t*)(dp + f * 16) = (uint32_t)w0;
    }
  }
  __syncthreads();   // lnbuf write-after-read guard between tiles

  // ---------------- tile 1 ----------------
  {
    f32x4 acc[8];
#pragma unroll
    for (int f = 0; f < 8; ++f) acc[f] = (f32x4){0.f, 0.f, 0.f, 0.f};
#pragma unroll
    for (int f = 0; f < 8; ++f)
#pragma unroll
      for (int s = 0; s < 4; ++s) {
        s16x8 w = *(const s16x8*)&Wl[(((wc * 8 + f) * 4 + s) * 64 + lane) * 8];
        acc[f] = __builtin_amdgcn_mfma_f32_16x16x32_bf16(w, a1[s], acc[f], 0, 0, 0);
      }
    float s1 = 0.f, s2 = 0.f;
#pragma unroll
    for (int f = 0; f < 8; ++f) {
      f32x4 bb = *(const f32x4*)(b1 + wc * 128 + f * 16 + l4 * 4);
#pragma unroll
      for (int j = 0; j < 4; ++j) {
        float v = acc[f][j] + bb[j];
        acc[f][j] = v;
        s1 += v; s2 += v * v;
      }
    }
    s1 += __shfl_xor(s1, 16); s1 += __shfl_xor(s1, 32);
    s2 += __shfl_xor(s2, 16); s2 += __shfl_xor(s2, 32);
    if (lane < 16) { lnbuf[wv][l15][0] = s1; lnbuf[wv][l15][1] = s2; }
    __syncthreads();
    float t1 = s1 + lnbuf[wv ^ 1][l15][0];
    float t2 = s2 + lnbuf[wv ^ 1][l15][1];
    float mu = t1 * (1.f / GCH);
    float var = t2 * (1.f / GCH) - mu * mu;
    float rs = rsqrtf(var + 1e-6f);
    uint8_t* dp = h1f8 + gr1 * GCH + wc * 128 + l4 * 4;
#pragma unroll
    for (int f = 0; f < 8; ++f) {
      f32x4 g4 = *(const f32x4*)(ln_g + wc * 128 + f * 16 + l4 * 4);
      f32x4 b4 = *(const f32x4*)(ln_b + wc * 128 + f * 16 + l4 * 4);
      float v0 = (acc[f][0] - mu) * rs * g4[0] + b4[0];
      float v1 = (acc[f][1] - mu) * rs * g4[1] + b4[1];
      float v2 = (acc[f][2] - mu) * rs * g4[2] + b4[2];
      float v3 = (acc[f][3] - mu) * rs * g4[3] + b4[3];
      int w0 = __builtin_amdgcn_cvt_pk_fp8_f32(v0, v1, 0, false);
      w0 = __builtin_amdgcn_cvt_pk_fp8_f32(v2, v3, w0, true);
      if (ok1) *(uint32_t*)(dp + f * 16) = (uint32_t)w0;
    }
  }
}

// ---------- K2+K4 fused: gather -> fp8 LDS tile -> fp8 MFMA -> gelu -> h3 fp8 ----------
// r14 body (wf 27.6 KB layout, LDS 76.8 KB = 2 blocks/CU) + h3 LDS repack
// epilogue (full 128-B-row coalesced stores, no write amplification).
__global__ __launch_bounds__(512) void k_dwg2(
    const uint8_t* __restrict__ h1f8, const int* __restrict__ nbr,
    const float* __restrict__ dw_w, const float* __restrict__ dw_b,
    const uint8_t* __restrict__ W2t8, const float* __restrict__ b2,
    uint8_t* __restrict__ h3f8, float* __restrict__ sums) {
  __shared__ float wf[KTAP * 4 * 16 * 4];   // 27648 B [k][j][l15][4] (2-way banks, free)
  __shared__ int idxl[128 * KTAP];          // 13824 B
  __shared__ uint8_t Al[128][GCH + 16];     // 34816 B fp8 h2 tile; reused as h3 tile [128][144]
  __shared__ float ssum[COUT];              // 512 B   -> 76800 B total, 2 blocks/CU
  int tid = threadIdx.x, lane = tid & 63, wv = tid >> 6;
  int l15 = lane & 15, l4 = lane >> 4;
  size_t pblk = (size_t)blockIdx.x * 128;

  for (int u = tid; u < KTAP * 64; u += 512) {   // stage dw weights f32
    int g = u >> 4, ld = u & 15, k = g >> 2, j = g & 3;
    *(f32x4*)&wf[u * 4] = *(const f32x4*)(dw_w + k * GCH + ld * 16 + j * 4);
  }
  if (tid < COUT) ssum[tid] = 0.f;
  for (int i = tid; i < 128 * KTAP; i += 512) {  // stage indices
    size_t gi = pblk * KTAP + i;
    idxl[i] = (gi < (size_t)NPTS * KTAP) ? __builtin_nontemporal_load(nbr + gi) : 0;
  }
  __syncthreads();

  {                                              // ---- gather phase ----
    f32x2 bias[8];
#pragma unroll
    for (int d = 0; d < 4; ++d) {
      f32x4 b4 = *(const f32x4*)(dw_b + l15 * 16 + d * 4);
      bias[2 * d]     = (f32x2){b4[0], b4[1]};
      bias[2 * d + 1] = (f32x2){b4[2], b4[3]};
    }
    int coff = l15 * 16;
#pragma unroll
    for (int it = 0; it < 4; ++it) {
      int pl = it * 32 + wv * 4 + l4;            // 0..127
      f32x2 acc[8];
#pragma unroll
      for (int i = 0; i < 8; ++i) acc[i] = bias[i];
#pragma unroll
      for (int k = 0; k < KTAP; ++k) {
        int row = idxl[pl * KTAP + k];           // LDS broadcast per 16-lane group
        u32x4 hv = *(const u32x4*)(h1f8 + ((size_t)(uint32_t)row << 8) + coff);
#pragma unroll
        for (int j = 0; j < 4; ++j) {
          f32x4 w4 = *(const f32x4*)&wf[((k * 4 + j) * 16 + l15) * 4];
          f32x2 lo = __builtin_amdgcn_cvt_pk_f32_fp8(hv[j], false);
          f32x2 hi = __builtin_amdgcn_cvt_pk_f32_fp8(hv[j], true);
          acc[2 * j]     += lo * (f32x2){w4[0], w4[1]};
          acc[2 * j + 1] += hi * (f32x2){w4[2], w4[3]};
        }
      }
      u32x4 o;
#pragma unroll
      for (int j = 0; j < 4; ++j) {
        int u = __builtin_amdgcn_cvt_pk_fp8_f32(acc[2 * j][0], acc[2 * j][1], 0, false);
        u = __builtin_amdgcn_cvt_pk_fp8_f32(acc[2 * j + 1][0], acc[2 * j + 1][1], u, true);
        o[j] = (uint32_t)u;
      }
      *(u32x4*)&Al[pl][coff] = o;                // h2 tile stays in LDS
    }
  }
  __syncthreads();

  // ---- MFMA phase (fp8 h2-tile @ W2) ----
  f32x4 acc[8];
#pragma unroll
  for (int f = 0; f < 8; ++f) acc[f] = (f32x4){0.f, 0.f, 0.f, 0.f};
  long aa[8];
#pragma unroll
  for (int s = 0; s < 8; ++s)
    aa[s] = *(const long*)&Al[wv * 16 + l15][s * 32 + l4 * 8];
  __syncthreads();                               // all Al reads done -> reuse as h3 tile
#pragma unroll
  for (int f = 0; f < 8; ++f)
#pragma unroll
    for (int s = 0; s < 8; ++s) {
      long bb = *(const long*)&W2t8[((f * 8 + s) * 64 + lane) * 8];  // L2-hot 32 KB
      acc[f] = __builtin_amdgcn_mfma_f32_16x16x32_fp8_fp8(aa[s], bb, acc[f], 0, 0, 0);
    }

  uint8_t* h3l = &Al[0][0];                      // [128][144] byte tile
#pragma unroll
  for (int f = 0; f < 8; ++f) {
    int col = f * 16 + l15;
    float bbv = b2[col];
    float ps = 0.f;
#pragma unroll
    for (int j = 0; j < 4; ++j) {
      int rl = wv * 16 + l4 * 4 + j;
      float v = acc[f][j] + bbv;
      // tanh-GELU in sigmoid form (max |diff| vs erf-GELU ~3e-4)
      float u = 1.5957691216f * (v + 0.044715f * v * v * v);
      float g = v * __frcp_rn(1.f + __expf(-u));
      uint32_t w8 = (uint32_t)__builtin_amdgcn_cvt_pk_fp8_f32(g, g, 0, false);
      h3l[rl * 144 + col] = (uint8_t)(w8 & 0xFF);
      if ((long)pblk + rl < NPTS) ps += g * g;
    }
    ps += __shfl_xor(ps, 16);
    ps += __shfl_xor(ps, 32);
    if (l4 == 0) atomicAdd(&ssum[col], ps);
  }
  __syncthreads();

  // coalesced write-out: 8 threads/row, full 128-B rows per instruction
#pragma unroll
  for (int p = 0; p < 2; ++p) {
    int row = p * 64 + (tid >> 3);
    long r = (long)pblk + row;
    if (r < NPTS) {
      u32x4 q = *(const u32x4*)&h3l[row * 144 + (tid & 7) * 16];
      __builtin_nontemporal_store(q, (u32x4*)(h3f8 + r * COUT + (tid & 7) * 16));
    }
  }
  if (tid < COUT) atomicAdd(&sums[tid], ssum[tid]);
}

// ---------- K5: GRN finalize -> scale/shift tables ----------
__global__ void k_grn(const float* __restrict__ sums, const float* __restrict__ grn_g,
                      const float* __restrict__ grn_b, float* __restrict__ sAB) {
  __shared__ float gx[COUT];
  __shared__ float mean_s;
  int t = threadIdx.x;
  float g = sqrtf(sums[t]);
  gx[t] = g;
  __syncthreads();
  if (t == 0) {
    float s = 0.f;
    for (int i = 0; i < COUT; ++i) s += gx[i];
    mean_s = s * (1.f / COUT);
  }
  __syncthreads();
  float nx = g / (mean_s + 1e-6f);
  sAB[t] = grn_g[t] * nx + 1.f;
  sAB[COUT + t] = grn_b[t];
}

// ---------- K6: out = h3*sA + sB + x (h3 is fp8) ----------
__global__ __launch_bounds__(256) void k_final(
    const uint8_t* __restrict__ h3f8, const float* __restrict__ x,
    const float* __restrict__ sAB, float* __restrict__ out) {
  long q = (long)blockIdx.x * 256 + threadIdx.x;
  long idx = q * 4;
  int c0 = (int)(idx & (COUT - 1));
  f32x4 sA = *(const f32x4*)(sAB + c0);
  f32x4 sB = *(const f32x4*)(sAB + COUT + c0);
  uint32_t hv = *(const uint32_t*)(h3f8 + idx);
  f32x2 lo = __builtin_amdgcn_cvt_pk_f32_fp8(hv, false);
  f32x2 hi = __builtin_amdgcn_cvt_pk_f32_fp8(hv, true);
  f32x4 xv = __builtin_nontemporal_load((const f32x4*)(x + idx));
  f32x4 r;
  r[0] = lo[0] * sA[0] + sB[0] + xv[0];
  r[1] = lo[1] * sA[1] + sB[1] + xv[1];
  r[2] = hi[0] * sA[2] + sB[2] + xv[2];
  r[3] = hi[1] * sA[3] + sB[3] + xv[3];
  __builtin_nontemporal_store(r, (f32x4*)(out + idx));
}

extern "C" void kernel_launch(void* const* d_in, const int* in_sizes, int n_in,
                              void* d_out, int out_size, void* d_ws, size_t ws_size,
                              hipStream_t stream) {
  const float* x     = (const float*)d_in[0];
  const int*   nbr   = (const int*)d_in[1];
  const float* W1    = (const float*)d_in[2];
  const float* b1    = (const float*)d_in[3];
  const float* ln_g  = (const float*)d_in[4];
  const float* ln_b  = (const float*)d_in[5];
  const float* dw_w  = (const float*)d_in[6];
  const float* dw_b  = (const float*)d_in[7];
  const float* W2    = (const float*)d_in[8];
  const float* b2    = (const float*)d_in[9];
  const float* grn_g = (const float*)d_in[10];
  const float* grn_b = (const float*)d_in[11];
  float* out = (float*)d_out;

  char* ws = (char*)d_ws;
  uint8_t* h1f8       = (uint8_t*)ws;                                // 128 MB
  uint8_t* h3f8       = (uint8_t*)(ws + (size_t)NPTS * GCH);         // 64 MB
  size_t off = (size_t)NPTS * GCH + (size_t)NPTS * COUT;             // 192 MB
  unsigned short* W1t = (unsigned short*)(ws + off);                 // 64 KB
  uint8_t* W2t8       = (uint8_t*)(ws + off + 65536);                // 32 KB
  float* sums         = (float*)(ws + off + 65536 + 32768);
  float* sAB          = (float*)(ws + off + 65536 + 32768 + 512);

  k_prep<<<32, 256, 0, stream>>>(W1, W2, W1t, W2t8, sums);
  k_gemm1_ln<<<(NPTS + 127) / 128, 512, 0, stream>>>(x, W1t, b1, ln_g, ln_b, h1f8);
  k_dwg2<<<(NPTS + 127) / 128, 512, 0, stream>>>(h1f8, nbr, dw_w, dw_b, W2t8, b2, h3f8, sums);
  k_grn<<<1, COUT, 0, stream>>>(sums, grn_g, grn_b, sAB);
  k_final<<<(NPTS * COUT / 4) / 256, 256, 0, stream>>>(h3f8, x, sAB, out);
}